// Round 8
// baseline (353.810 us; speedup 1.0000x reference)
//
#include <hip/hip_runtime.h>
#include <cstddef>

#define HIDDEN 128
#define BN_EPS 1e-5f
#define SCAN_CHUNK 1024  // cnt elements per scan block
#define KS 136           // GEMM LDS row stride (ushort): 272B = 17*16B -> aligned b128

typedef __attribute__((ext_vector_type(8))) short short8;    // 8 bf16 (4 VGPRs)
typedef __attribute__((ext_vector_type(4))) float float4v;   // MFMA acc / NT lds
typedef __attribute__((ext_vector_type(2))) float float2v;
typedef __attribute__((ext_vector_type(4))) unsigned uint4v;

// RNE float->bf16 (manual, exact for non-NaN)
__device__ inline unsigned bf16_rne(float f) {
    unsigned u = __float_as_uint(f);
    return (u + 0x7fff + ((u >> 16) & 1)) >> 16;
}

// ---------- K1: in-degree histogram (int4-vectorized col reads) ----------
__global__ void k_count(const int* __restrict__ col, int* __restrict__ cnt, int E) {
    int base = (blockIdx.x * 256 + threadIdx.x) * 4;
    if (base + 3 < E) {
        int4 c = *(const int4*)&col[base];
        atomicAdd(&cnt[c.x], 1);
        atomicAdd(&cnt[c.y], 1);
        atomicAdd(&cnt[c.z], 1);
        atomicAdd(&cnt[c.w], 1);
    } else {
        for (int k = 0; k < 4; ++k) {
            int e = base + k;
            if (e < E) atomicAdd(&cnt[col[e]], 1);
        }
    }
}

// ---------- K2: fused CSR-build scan (decoupled lookback, 1 dispatch) ----------
__global__ __launch_bounds__(256) void k_csr(int* __restrict__ cnt,
                                             unsigned long long* __restrict__ flags,
                                             int* __restrict__ off,
                                             float* __restrict__ dinv, int N, int NB) {
    __shared__ int s[256];
    __shared__ int sbase;
    int tid = threadIdx.x;
    int b = blockIdx.x;
    int base = b * SCAN_CHUNK;
    int c[4];
    int t = 0;
#pragma unroll
    for (int k = 0; k < 4; ++k) {
        int idx = base + tid * 4 + k;
        c[k] = (idx < N) ? cnt[idx] : 0;
        t += c[k];
    }
    s[tid] = t;
    __syncthreads();
    for (int o = 1; o < 256; o <<= 1) {
        int v = (tid >= o) ? s[tid - o] : 0;
        __syncthreads();
        s[tid] += v;
        __syncthreads();
    }
    int incl = s[tid];
    int total = s[255];

    if (b == 0) {
        if (tid == 0) {
            sbase = 0;
            atomicExch(&flags[0], (2ULL << 32) | (unsigned)total);
        }
    } else {
        if (tid == 0) atomicExch(&flags[b], (1ULL << 32) | (unsigned)total);
        if (tid < 64) {  // wave-0 parallel lookback
            int excl = 0;
            int look = b - 1;
            while (true) {
                int idx = look - tid;
                unsigned long long v = 0;
                if (idx >= 0) {
                    do { v = atomicAdd(&flags[idx], 0ULL); } while ((v >> 32) == 0ULL);
                }
                int st = (int)(v >> 32);
                unsigned long long ball = __ballot(idx >= 0 && st == 2);
                int firstInc = ball ? (__ffsll(ball) - 1) : 64;
                int val = (idx >= 0 && tid <= firstInc) ? (int)(v & 0xffffffffULL) : 0;
#pragma unroll
                for (int o = 32; o > 0; o >>= 1) val += __shfl_down(val, o);
                if (tid == 0) excl += val;
                if (firstInc < 64 || look - 64 < 0) break;
                look -= 64;
            }
            if (tid == 0) {
                sbase = excl;
                atomicExch(&flags[b], (2ULL << 32) | (unsigned)(excl + total));
            }
        }
    }
    __syncthreads();

    int run = sbase + incl - t;
#pragma unroll
    for (int k = 0; k < 4; ++k) {
        int idx = base + tid * 4 + k;
        if (idx < N) {
            off[idx] = run;
            run += c[k];
            dinv[idx] = rsqrtf((float)(c[k] + 1));  // deg includes self-loop
            cnt[idx] = 0;                           // reused as cursor in k_place
        }
    }
    if (b == NB - 1 && tid == 255) off[N] = sbase + incl;
}

// ---------- K3: xu(bf16) = dinv .* (x @ W) via bf16 MFMA ----------
// 128x128 tile/block, K=128 staged once as bf16 in LDS. NT x loads (read-once).
// Epilogue bounces C through lA -> fully-coalesced uint4 stores.
__global__ __launch_bounds__(256) void k_gemm(const float* __restrict__ x,
                                              const float* __restrict__ W,
                                              const float* __restrict__ dinv,
                                              unsigned short* __restrict__ xus, int N) {
    __shared__ unsigned short lA[128 * KS];  // [m][k] bf16, reused for C bounce
    __shared__ unsigned short lB[128 * KS];  // [n][k] bf16 (W transposed)
    int tid = threadIdx.x;
    int row0 = blockIdx.x * 128;
    int wv = tid >> 6;
    int lane = tid & 63;
    int l15 = lane & 15;
    int lq = lane >> 4;  // 0..3

    // stage x tile: NT float4 loads (streamed once, keep L3 for xu)
    for (int it = 0; it < 16; ++it) {
        int idx4 = it * 256 + tid;
        int m = idx4 >> 5, c4 = idx4 & 31;
        int grow = row0 + m;
        float4v v = {0.f, 0.f, 0.f, 0.f};
        if (grow < N) v = __builtin_nontemporal_load((const float4v*)x + (size_t)grow * 32 + c4);
        uint2 pk;
        pk.x = bf16_rne(v.x) | (bf16_rne(v.y) << 16);
        pk.y = bf16_rne(v.z) | (bf16_rne(v.w) << 16);
        *(uint2*)&lA[m * KS + c4 * 4] = pk;
    }
    // stage W transposed: float4 reads (4 cols), scattered b16 LDS writes
    for (int it = 0; it < 16; ++it) {
        int idx4 = it * 256 + tid;               // 4096 float4
        int k = idx4 >> 5, n4 = idx4 & 31;       // n = 4*n4
        float4v v = *((const float4v*)W + (size_t)k * 32 + n4);
        int n = n4 * 4;
        lB[(n + 0) * KS + k] = (unsigned short)bf16_rne(v.x);
        lB[(n + 1) * KS + k] = (unsigned short)bf16_rne(v.y);
        lB[(n + 2) * KS + k] = (unsigned short)bf16_rne(v.z);
        lB[(n + 3) * KS + k] = (unsigned short)bf16_rne(v.w);
    }
    __syncthreads();

    float4v acc[2][8];
#pragma unroll
    for (int i = 0; i < 2; ++i)
#pragma unroll
        for (int j = 0; j < 8; ++j) acc[i][j] = (float4v){0.f, 0.f, 0.f, 0.f};

#pragma unroll
    for (int kc = 0; kc < 4; ++kc) {
        int ko = kc * 32 + lq * 8;
        short8 a0 = *(const short8*)&lA[(wv * 32 + l15) * KS + ko];
        short8 a1 = *(const short8*)&lA[(wv * 32 + 16 + l15) * KS + ko];
        short8 bfr[8];
#pragma unroll
        for (int nt = 0; nt < 8; ++nt)
            bfr[nt] = *(const short8*)&lB[(nt * 16 + l15) * KS + ko];
#pragma unroll
        for (int nt = 0; nt < 8; ++nt) {
            acc[0][nt] = __builtin_amdgcn_mfma_f32_16x16x32_bf16(a0, bfr[nt], acc[0][nt], 0, 0, 0);
            acc[1][nt] = __builtin_amdgcn_mfma_f32_16x16x32_bf16(a1, bfr[nt], acc[1][nt], 0, 0, 0);
        }
    }

    __syncthreads();  // all lA fragment reads done before C bounce

    // bounce C into lA as bf16 (scattered b16 LDS writes, cheap)
#pragma unroll
    for (int mt = 0; mt < 2; ++mt) {
#pragma unroll
        for (int reg = 0; reg < 4; ++reg) {
            int rl = wv * 32 + mt * 16 + lq * 4 + reg;  // local row
            int r = row0 + rl;
            float d = (r < N) ? dinv[r] : 0.f;
#pragma unroll
            for (int nt = 0; nt < 8; ++nt)
                lA[rl * KS + nt * 16 + l15] = (unsigned short)bf16_rne(acc[mt][nt][reg] * d);
        }
    }
    __syncthreads();

    // coalesced store: 128 rows x 16 uint4 (256B/row)
    for (int it = 0; it < 8; ++it) {
        int idx = it * 256 + tid;
        int r = idx >> 4, c16 = idx & 15;
        int grow = row0 + r;
        if (grow < N) {
            uint4v v = *(const uint4v*)&lA[r * KS + c16 * 8];
            *((uint4v*)(xus + (size_t)grow * 128) + c16) = v;
        }
    }
}

// ---------- K4: counting-sort edges by target (4 edges/thread, int4) ----------
__global__ void k_place(const int* __restrict__ row, const int* __restrict__ col,
                        const int* __restrict__ off, int* __restrict__ cur,
                        int* __restrict__ srcs, int E) {
    int base = (blockIdx.x * 256 + threadIdx.x) * 4;
    if (base + 3 < E) {
        int4 c = *(const int4*)&col[base];
        int4 r = *(const int4*)&row[base];
        int p0 = atomicAdd(&cur[c.x], 1);
        int p1 = atomicAdd(&cur[c.y], 1);
        int p2 = atomicAdd(&cur[c.z], 1);
        int p3 = atomicAdd(&cur[c.w], 1);
        srcs[off[c.x] + p0] = r.x;
        srcs[off[c.y] + p1] = r.y;
        srcs[off[c.z] + p2] = r.z;
        srcs[off[c.w] + p3] = r.w;
    } else {
        for (int k = 0; k < 4; ++k) {
            int e = base + k;
            if (e < E) {
                int c = col[e];
                int p = atomicAdd(&cur[c], 1);
                srcs[off[c] + p] = row[e];
            }
        }
    }
}

// ---------- K5: gather-aggregate (bf16 rows, 8 in flight, NT out) + BN stats ----------
__global__ __launch_bounds__(256) void k_gather(const unsigned* __restrict__ xu,
                                                const float* __restrict__ dinv,
                                                const int* __restrict__ off,
                                                const int* __restrict__ srcs,
                                                const float* __restrict__ b,
                                                float* __restrict__ out,
                                                float* __restrict__ bn, int N) {
    int tid = threadIdx.x;
    int lane = tid & 63;
    int w = (blockIdx.x * 256 + tid) >> 6;
    int nw = (gridDim.x * 256) >> 6;
    float2 bb = ((const float2*)b)[lane];
    float2 s = make_float2(0.f, 0.f), qq = make_float2(0.f, 0.f);
    for (int i = w; i < N; i += nw) {
        float di = dinv[i];
        unsigned su = xu[(size_t)i * 64 + lane];  // self-loop (pre-scaled)
        float ax = __uint_as_float(su << 16);
        float ay = __uint_as_float(su & 0xffff0000u);
        int e0 = off[i], e1 = off[i + 1];
        int j = e0;
        for (; j + 8 <= e1; j += 8) {
            int r[8];
#pragma unroll
            for (int k = 0; k < 8; ++k) r[k] = srcs[j + k];
            unsigned u[8];
#pragma unroll
            for (int k = 0; k < 8; ++k) u[k] = xu[(size_t)r[k] * 64 + lane];
#pragma unroll
            for (int k = 0; k < 8; ++k) {
                ax += __uint_as_float(u[k] << 16);
                ay += __uint_as_float(u[k] & 0xffff0000u);
            }
        }
        for (; j + 4 <= e1; j += 4) {
            int r0 = srcs[j], r1 = srcs[j + 1], r2 = srcs[j + 2], r3 = srcs[j + 3];
            unsigned u0 = xu[(size_t)r0 * 64 + lane];
            unsigned u1 = xu[(size_t)r1 * 64 + lane];
            unsigned u2 = xu[(size_t)r2 * 64 + lane];
            unsigned u3 = xu[(size_t)r3 * 64 + lane];
            ax += __uint_as_float(u0 << 16) + __uint_as_float(u1 << 16)
                + __uint_as_float(u2 << 16) + __uint_as_float(u3 << 16);
            ay += __uint_as_float(u0 & 0xffff0000u) + __uint_as_float(u1 & 0xffff0000u)
                + __uint_as_float(u2 & 0xffff0000u) + __uint_as_float(u3 & 0xffff0000u);
        }
        for (; j < e1; ++j) {
            int r = srcs[j];
            unsigned u = xu[(size_t)r * 64 + lane];
            ax += __uint_as_float(u << 16);
            ay += __uint_as_float(u & 0xffff0000u);
        }
        float ox = fmaf(ax, di, bb.x);
        float oy = fmaf(ay, di, bb.y);
        float2v o2 = {ox, oy};  // NT: don't let out-stream evict xu from L3
        __builtin_nontemporal_store(o2, (float2v*)out + (size_t)i * 64 + lane);
        s.x += ox;
        s.y += oy;
        qq.x = fmaf(ox, ox, qq.x);
        qq.y = fmaf(oy, oy, qq.y);
    }
    __shared__ float ssum[HIDDEN];
    __shared__ float ssq[HIDDEN];
    if (tid < HIDDEN) { ssum[tid] = 0.f; ssq[tid] = 0.f; }
    __syncthreads();
    atomicAdd(&ssum[2 * lane],     s.x);
    atomicAdd(&ssum[2 * lane + 1], s.y);
    atomicAdd(&ssq[2 * lane],      qq.x);
    atomicAdd(&ssq[2 * lane + 1],  qq.y);
    __syncthreads();
    if (tid < HIDDEN) {
        atomicAdd(&bn[tid],          ssum[tid]);
        atomicAdd(&bn[HIDDEN + tid], ssq[tid]);
    }
}

// ---------- K6: BN normalize + gamma/beta + ReLU, in place (NT streaming) ----------
__global__ __launch_bounds__(256) void k_apply(float* __restrict__ out,
                                               const float* __restrict__ bn,
                                               const float* __restrict__ gamma,
                                               const float* __restrict__ beta,
                                               int total4, float invN) {
    __shared__ float sc[HIDDEN], sh[HIDDEN];
    int tid = threadIdx.x;
    if (tid < HIDDEN) {
        float mean = bn[tid] * invN;
        float var = bn[HIDDEN + tid] * invN - mean * mean;
        float inv = rsqrtf(var + BN_EPS);
        float g = gamma[tid] * inv;
        sc[tid] = g;
        sh[tid] = beta[tid] - mean * g;
    }
    __syncthreads();
    int idx = blockIdx.x * 256 + tid;
    if (idx < total4) {
        float4v v = __builtin_nontemporal_load((float4v*)out + idx);
        int c = (idx & 31) * 4;
        v.x = fmaxf(fmaf(v.x, sc[c],     sh[c]),     0.f);
        v.y = fmaxf(fmaf(v.y, sc[c + 1], sh[c + 1]), 0.f);
        v.z = fmaxf(fmaf(v.z, sc[c + 2], sh[c + 2]), 0.f);
        v.w = fmaxf(fmaf(v.w, sc[c + 3], sh[c + 3]), 0.f);
        __builtin_nontemporal_store(v, (float4v*)out + idx);
    }
}

extern "C" void kernel_launch(void* const* d_in, const int* in_sizes, int n_in,
                              void* d_out, int out_size, void* d_ws, size_t ws_size,
                              hipStream_t stream) {
    const float* x     = (const float*)d_in[0];
    const int*   edges = (const int*)d_in[1];   // [2, E] int32 (JAX x64-off)
    const float* W     = (const float*)d_in[2];
    const float* b     = (const float*)d_in[3];
    const float* gamma = (const float*)d_in[4];
    const float* beta  = (const float*)d_in[5];
    float* out = (float*)d_out;

    int N = in_sizes[0] / HIDDEN;
    int E = in_sizes[1] / 2;
    const int* row = edges;      // sources
    const int* col = edges + E;  // targets

    int NB = (N + SCAN_CHUNK - 1) / SCAN_CHUNK;

    // workspace carve (~31 MB). Zeroed region contiguous: cnt | flags | bn.
    char* p = (char*)d_ws;
    unsigned* xu = (unsigned*)p; p += (size_t)N * 64 * sizeof(unsigned);  // 128 bf16/row
    float* dinv  = (float*)p; p += (size_t)N * sizeof(float);
    int*   cnt   = (int*)p;   p += (size_t)N * sizeof(int);               // zeroed
    unsigned long long* flags = (unsigned long long*)p;
    p += (size_t)NB * sizeof(unsigned long long);                         // zeroed
    float* bn    = (float*)p; p += 256 * sizeof(float);                   // zeroed
    int*   off   = (int*)p;   p += ((size_t)N + 4) * sizeof(int);
    int*   srcs  = (int*)p;   p += (size_t)E * sizeof(int);

    size_t zbytes = (size_t)N * sizeof(int) + (size_t)NB * sizeof(unsigned long long)
                  + 256 * sizeof(float);

    dim3 blk(256);
    hipMemsetAsync(cnt, 0, zbytes, stream);
    k_count<<<dim3((E + 1023) / 1024), blk, 0, stream>>>(col, cnt, E);
    k_csr<<<dim3(NB), blk, 0, stream>>>(cnt, flags, off, dinv, N, NB);
    k_gemm<<<dim3((N + 127) / 128), blk, 0, stream>>>(x, W, dinv, (unsigned short*)xu, N);
    k_place<<<dim3((E + 1023) / 1024), blk, 0, stream>>>(row, col, off, cnt, srcs, E);
    k_gather<<<dim3(2048), blk, 0, stream>>>(xu, dinv, off, srcs, b, out, bn, N);
    int total4 = N * (HIDDEN / 4);
    k_apply<<<dim3((total4 + 255) / 256), blk, 0, stream>>>(out, bn, gamma, beta, total4,
                                                            1.0f / (float)N);
}

// Round 9
// 331.403 us; speedup vs baseline: 1.0676x; 1.0676x over previous
//
#include <hip/hip_runtime.h>
#include <cstddef>

#define HIDDEN 128
#define BN_EPS 1e-5f
#define SCAN_CHUNK 1024  // cnt elements per scan block
#define KS 136           // GEMM LDS row stride (ushort): 272B = 17*16B -> aligned b128

typedef __attribute__((ext_vector_type(8))) short short8;    // 8 bf16 (4 VGPRs)
typedef __attribute__((ext_vector_type(4))) float float4v;   // MFMA acc
typedef __attribute__((ext_vector_type(4))) unsigned uint4v;

// RNE float->bf16 (manual, exact for non-NaN)
__device__ inline unsigned bf16_rne(float f) {
    unsigned u = __float_as_uint(f);
    return (u + 0x7fff + ((u >> 16) & 1)) >> 16;
}
__device__ inline unsigned pack2_bf16(float a, float b) {
    return bf16_rne(a) | (bf16_rne(b) << 16);
}

// ---------- K1: in-degree histogram (int4-vectorized col reads) ----------
__global__ void k_count(const int* __restrict__ col, int* __restrict__ cnt, int E) {
    int base = (blockIdx.x * 256 + threadIdx.x) * 4;
    if (base + 3 < E) {
        int4 c = *(const int4*)&col[base];
        atomicAdd(&cnt[c.x], 1);
        atomicAdd(&cnt[c.y], 1);
        atomicAdd(&cnt[c.z], 1);
        atomicAdd(&cnt[c.w], 1);
    } else {
        for (int k = 0; k < 4; ++k) {
            int e = base + k;
            if (e < E) atomicAdd(&cnt[col[e]], 1);
        }
    }
}

// ---------- K2: fused CSR-build scan (decoupled lookback, 1 dispatch) ----------
__global__ __launch_bounds__(256) void k_csr(int* __restrict__ cnt,
                                             unsigned long long* __restrict__ flags,
                                             int* __restrict__ off,
                                             float* __restrict__ dinv, int N, int NB) {
    __shared__ int s[256];
    __shared__ int sbase;
    int tid = threadIdx.x;
    int b = blockIdx.x;
    int base = b * SCAN_CHUNK;
    int c[4];
    int t = 0;
#pragma unroll
    for (int k = 0; k < 4; ++k) {
        int idx = base + tid * 4 + k;
        c[k] = (idx < N) ? cnt[idx] : 0;
        t += c[k];
    }
    s[tid] = t;
    __syncthreads();
    for (int o = 1; o < 256; o <<= 1) {
        int v = (tid >= o) ? s[tid - o] : 0;
        __syncthreads();
        s[tid] += v;
        __syncthreads();
    }
    int incl = s[tid];
    int total = s[255];

    if (b == 0) {
        if (tid == 0) {
            sbase = 0;
            atomicExch(&flags[0], (2ULL << 32) | (unsigned)total);
        }
    } else {
        if (tid == 0) atomicExch(&flags[b], (1ULL << 32) | (unsigned)total);
        if (tid < 64) {  // wave-0 parallel lookback
            int excl = 0;
            int look = b - 1;
            while (true) {
                int idx = look - tid;
                unsigned long long v = 0;
                if (idx >= 0) {
                    do { v = atomicAdd(&flags[idx], 0ULL); } while ((v >> 32) == 0ULL);
                }
                int st = (int)(v >> 32);
                unsigned long long ball = __ballot(idx >= 0 && st == 2);
                int firstInc = ball ? (__ffsll(ball) - 1) : 64;
                int val = (idx >= 0 && tid <= firstInc) ? (int)(v & 0xffffffffULL) : 0;
#pragma unroll
                for (int o = 32; o > 0; o >>= 1) val += __shfl_down(val, o);
                if (tid == 0) excl += val;
                if (firstInc < 64 || look - 64 < 0) break;
                look -= 64;
            }
            if (tid == 0) {
                sbase = excl;
                atomicExch(&flags[b], (2ULL << 32) | (unsigned)(excl + total));
            }
        }
    }
    __syncthreads();

    int run = sbase + incl - t;
#pragma unroll
    for (int k = 0; k < 4; ++k) {
        int idx = base + tid * 4 + k;
        if (idx < N) {
            off[idx] = run;
            run += c[k];
            dinv[idx] = rsqrtf((float)(c[k] + 1));  // deg includes self-loop
            cnt[idx] = 0;                           // reused as cursor in k_place
        }
    }
    if (b == NB - 1 && tid == 255) off[N] = sbase + incl;
}

// ---------- K3: xu(bf16) = dinv .* (x @ W) via bf16 MFMA ----------
// 128x128 tile/block, K=128 staged once as bf16 in LDS. Epilogue bounces C
// through lA -> fully-coalesced uint4 stores. (No NT: it regressed in R8.)
__global__ __launch_bounds__(256) void k_gemm(const float* __restrict__ x,
                                              const float* __restrict__ W,
                                              const float* __restrict__ dinv,
                                              unsigned short* __restrict__ xus, int N) {
    __shared__ unsigned short lA[128 * KS];  // [m][k] bf16, reused for C bounce
    __shared__ unsigned short lB[128 * KS];  // [n][k] bf16 (W transposed)
    int tid = threadIdx.x;
    int row0 = blockIdx.x * 128;
    int wv = tid >> 6;
    int lane = tid & 63;
    int l15 = lane & 15;
    int lq = lane >> 4;  // 0..3

    for (int it = 0; it < 16; ++it) {
        int idx4 = it * 256 + tid;
        int m = idx4 >> 5, c4 = idx4 & 31;
        int grow = row0 + m;
        float4 v = make_float4(0.f, 0.f, 0.f, 0.f);
        if (grow < N) v = ((const float4*)x)[(size_t)grow * 32 + c4];
        uint2 pk;
        pk.x = pack2_bf16(v.x, v.y);
        pk.y = pack2_bf16(v.z, v.w);
        *(uint2*)&lA[m * KS + c4 * 4] = pk;
    }
    for (int it = 0; it < 16; ++it) {
        int idx4 = it * 256 + tid;               // 4096 float4
        int k = idx4 >> 5, n4 = idx4 & 31;       // n = 4*n4
        float4 v = ((const float4*)W)[(size_t)k * 32 + n4];
        int n = n4 * 4;
        lB[(n + 0) * KS + k] = (unsigned short)bf16_rne(v.x);
        lB[(n + 1) * KS + k] = (unsigned short)bf16_rne(v.y);
        lB[(n + 2) * KS + k] = (unsigned short)bf16_rne(v.z);
        lB[(n + 3) * KS + k] = (unsigned short)bf16_rne(v.w);
    }
    __syncthreads();

    float4v acc[2][8];
#pragma unroll
    for (int i = 0; i < 2; ++i)
#pragma unroll
        for (int j = 0; j < 8; ++j) acc[i][j] = (float4v){0.f, 0.f, 0.f, 0.f};

#pragma unroll
    for (int kc = 0; kc < 4; ++kc) {
        int ko = kc * 32 + lq * 8;
        short8 a0 = *(const short8*)&lA[(wv * 32 + l15) * KS + ko];
        short8 a1 = *(const short8*)&lA[(wv * 32 + 16 + l15) * KS + ko];
        short8 bfr[8];
#pragma unroll
        for (int nt = 0; nt < 8; ++nt)
            bfr[nt] = *(const short8*)&lB[(nt * 16 + l15) * KS + ko];
#pragma unroll
        for (int nt = 0; nt < 8; ++nt) {
            acc[0][nt] = __builtin_amdgcn_mfma_f32_16x16x32_bf16(a0, bfr[nt], acc[0][nt], 0, 0, 0);
            acc[1][nt] = __builtin_amdgcn_mfma_f32_16x16x32_bf16(a1, bfr[nt], acc[1][nt], 0, 0, 0);
        }
    }

    __syncthreads();  // all lA fragment reads done before C bounce

    // bounce C into lA as bf16 (scattered b16 LDS writes, cheap)
#pragma unroll
    for (int mt = 0; mt < 2; ++mt) {
#pragma unroll
        for (int reg = 0; reg < 4; ++reg) {
            int rl = wv * 32 + mt * 16 + lq * 4 + reg;  // local row
            int r = row0 + rl;
            float d = (r < N) ? dinv[r] : 0.f;
#pragma unroll
            for (int nt = 0; nt < 8; ++nt)
                lA[rl * KS + nt * 16 + l15] = (unsigned short)bf16_rne(acc[mt][nt][reg] * d);
        }
    }
    __syncthreads();

    // coalesced store: 128 rows x 16 uint4 (256B/row)
    for (int it = 0; it < 8; ++it) {
        int idx = it * 256 + tid;
        int r = idx >> 4, c16 = idx & 15;
        int grow = row0 + r;
        if (grow < N) {
            uint4v v = *(const uint4v*)&lA[r * KS + c16 * 8];
            *((uint4v*)(xus + (size_t)grow * 128) + c16) = v;
        }
    }
}

// ---------- K4: counting-sort edges by target (4 edges/thread, int4) ----------
__global__ void k_place(const int* __restrict__ row, const int* __restrict__ col,
                        const int* __restrict__ off, int* __restrict__ cur,
                        int* __restrict__ srcs, int E) {
    int base = (blockIdx.x * 256 + threadIdx.x) * 4;
    if (base + 3 < E) {
        int4 c = *(const int4*)&col[base];
        int4 r = *(const int4*)&row[base];
        int p0 = atomicAdd(&cur[c.x], 1);
        int p1 = atomicAdd(&cur[c.y], 1);
        int p2 = atomicAdd(&cur[c.z], 1);
        int p3 = atomicAdd(&cur[c.w], 1);
        srcs[off[c.x] + p0] = r.x;
        srcs[off[c.y] + p1] = r.y;
        srcs[off[c.z] + p2] = r.z;
        srcs[off[c.w] + p3] = r.w;
    } else {
        for (int k = 0; k < 4; ++k) {
            int e = base + k;
            if (e < E) {
                int c = col[e];
                int p = atomicAdd(&cur[c], 1);
                srcs[off[c] + p] = row[e];
            }
        }
    }
}

// ---------- K5: gather-aggregate (bf16 rows, 8 in flight) + BN stats ----------
// agg written as bf16 (halves gather write lines + apply read lines).
// Stats computed on pre-quantization fp32 values.
__global__ __launch_bounds__(256) void k_gather(const unsigned* __restrict__ xu,
                                                const float* __restrict__ dinv,
                                                const int* __restrict__ off,
                                                const int* __restrict__ srcs,
                                                const float* __restrict__ b,
                                                unsigned* __restrict__ agg,
                                                float* __restrict__ bn, int N) {
    int tid = threadIdx.x;
    int lane = tid & 63;
    int w = (blockIdx.x * 256 + tid) >> 6;
    int nw = (gridDim.x * 256) >> 6;
    float2 bb = ((const float2*)b)[lane];
    float2 s = make_float2(0.f, 0.f), qq = make_float2(0.f, 0.f);
    for (int i = w; i < N; i += nw) {
        float di = dinv[i];
        unsigned su = xu[(size_t)i * 64 + lane];  // self-loop (pre-scaled)
        float ax = __uint_as_float(su << 16);
        float ay = __uint_as_float(su & 0xffff0000u);
        int e0 = off[i], e1 = off[i + 1];
        int j = e0;
        for (; j + 8 <= e1; j += 8) {
            int r[8];
#pragma unroll
            for (int k = 0; k < 8; ++k) r[k] = srcs[j + k];
            unsigned u[8];
#pragma unroll
            for (int k = 0; k < 8; ++k) u[k] = xu[(size_t)r[k] * 64 + lane];
#pragma unroll
            for (int k = 0; k < 8; ++k) {
                ax += __uint_as_float(u[k] << 16);
                ay += __uint_as_float(u[k] & 0xffff0000u);
            }
        }
        for (; j + 4 <= e1; j += 4) {
            int r0 = srcs[j], r1 = srcs[j + 1], r2 = srcs[j + 2], r3 = srcs[j + 3];
            unsigned u0 = xu[(size_t)r0 * 64 + lane];
            unsigned u1 = xu[(size_t)r1 * 64 + lane];
            unsigned u2 = xu[(size_t)r2 * 64 + lane];
            unsigned u3 = xu[(size_t)r3 * 64 + lane];
            ax += __uint_as_float(u0 << 16) + __uint_as_float(u1 << 16)
                + __uint_as_float(u2 << 16) + __uint_as_float(u3 << 16);
            ay += __uint_as_float(u0 & 0xffff0000u) + __uint_as_float(u1 & 0xffff0000u)
                + __uint_as_float(u2 & 0xffff0000u) + __uint_as_float(u3 & 0xffff0000u);
        }
        for (; j < e1; ++j) {
            int r = srcs[j];
            unsigned u = xu[(size_t)r * 64 + lane];
            ax += __uint_as_float(u << 16);
            ay += __uint_as_float(u & 0xffff0000u);
        }
        float ox = fmaf(ax, di, bb.x);
        float oy = fmaf(ay, di, bb.y);
        agg[(size_t)i * 64 + lane] = pack2_bf16(ox, oy);  // bf16 agg
        s.x += ox;
        s.y += oy;
        qq.x = fmaf(ox, ox, qq.x);
        qq.y = fmaf(oy, oy, qq.y);
    }
    __shared__ float ssum[HIDDEN];
    __shared__ float ssq[HIDDEN];
    if (tid < HIDDEN) { ssum[tid] = 0.f; ssq[tid] = 0.f; }
    __syncthreads();
    atomicAdd(&ssum[2 * lane],     s.x);
    atomicAdd(&ssum[2 * lane + 1], s.y);
    atomicAdd(&ssq[2 * lane],      qq.x);
    atomicAdd(&ssq[2 * lane + 1],  qq.y);
    __syncthreads();
    if (tid < HIDDEN) {
        atomicAdd(&bn[tid],          ssum[tid]);
        atomicAdd(&bn[HIDDEN + tid], ssq[tid]);
    }
}

// ---------- K6: BN normalize + gamma/beta + ReLU: bf16 agg -> fp32 out ----------
__global__ __launch_bounds__(256) void k_apply(const unsigned* __restrict__ agg,
                                               float* __restrict__ out,
                                               const float* __restrict__ bn,
                                               const float* __restrict__ gamma,
                                               const float* __restrict__ beta,
                                               int total8, float invN) {
    __shared__ float sc[HIDDEN], sh[HIDDEN];
    int tid = threadIdx.x;
    if (tid < HIDDEN) {
        float mean = bn[tid] * invN;
        float var = bn[HIDDEN + tid] * invN - mean * mean;
        float inv = rsqrtf(var + BN_EPS);
        float g = gamma[tid] * inv;
        sc[tid] = g;
        sh[tid] = beta[tid] - mean * g;
    }
    __syncthreads();
    int idx = blockIdx.x * 256 + tid;  // one uint2 = 4 cols
    if (idx < total8) {
        uint2 u = ((const uint2*)agg)[idx];
        int c = (idx & 31) * 4;
        float4 v;
        v.x = __uint_as_float(u.x << 16);
        v.y = __uint_as_float(u.x & 0xffff0000u);
        v.z = __uint_as_float(u.y << 16);
        v.w = __uint_as_float(u.y & 0xffff0000u);
        v.x = fmaxf(fmaf(v.x, sc[c],     sh[c]),     0.f);
        v.y = fmaxf(fmaf(v.y, sc[c + 1], sh[c + 1]), 0.f);
        v.z = fmaxf(fmaf(v.z, sc[c + 2], sh[c + 2]), 0.f);
        v.w = fmaxf(fmaf(v.w, sc[c + 3], sh[c + 3]), 0.f);
        ((float4*)out)[idx] = v;
    }
}

extern "C" void kernel_launch(void* const* d_in, const int* in_sizes, int n_in,
                              void* d_out, int out_size, void* d_ws, size_t ws_size,
                              hipStream_t stream) {
    const float* x     = (const float*)d_in[0];
    const int*   edges = (const int*)d_in[1];   // [2, E] int32 (JAX x64-off)
    const float* W     = (const float*)d_in[2];
    const float* b     = (const float*)d_in[3];
    const float* gamma = (const float*)d_in[4];
    const float* beta  = (const float*)d_in[5];
    float* out = (float*)d_out;

    int N = in_sizes[0] / HIDDEN;
    int E = in_sizes[1] / 2;
    const int* row = edges;      // sources
    const int* col = edges + E;  // targets

    int NB = (N + SCAN_CHUNK - 1) / SCAN_CHUNK;

    // workspace carve (~58 MB). Zeroed region contiguous: cnt | flags | bn.
    char* p = (char*)d_ws;
    unsigned* xu  = (unsigned*)p; p += (size_t)N * 64 * sizeof(unsigned);  // xw bf16
    unsigned* agg = (unsigned*)p; p += (size_t)N * 64 * sizeof(unsigned);  // agg bf16
    float* dinv   = (float*)p; p += (size_t)N * sizeof(float);
    int*   cnt    = (int*)p;   p += (size_t)N * sizeof(int);               // zeroed
    unsigned long long* flags = (unsigned long long*)p;
    p += (size_t)NB * sizeof(unsigned long long);                          // zeroed
    float* bn     = (float*)p; p += 256 * sizeof(float);                   // zeroed
    int*   off    = (int*)p;   p += ((size_t)N + 4) * sizeof(int);
    int*   srcs   = (int*)p;   p += (size_t)E * sizeof(int);

    size_t zbytes = (size_t)N * sizeof(int) + (size_t)NB * sizeof(unsigned long long)
                  + 256 * sizeof(float);

    dim3 blk(256);
    hipMemsetAsync(cnt, 0, zbytes, stream);
    k_count<<<dim3((E + 1023) / 1024), blk, 0, stream>>>(col, cnt, E);
    k_csr<<<dim3(NB), blk, 0, stream>>>(cnt, flags, off, dinv, N, NB);
    k_gemm<<<dim3((N + 127) / 128), blk, 0, stream>>>(x, W, dinv, (unsigned short*)xu, N);
    k_place<<<dim3((E + 1023) / 1024), blk, 0, stream>>>(row, col, off, cnt, srcs, E);
    k_gather<<<dim3(2048), blk, 0, stream>>>(xu, dinv, off, srcs, b, agg, bn, N);
    int total8 = N * 32;  // uint2 groups (4 cols each)
    k_apply<<<dim3((total8 + 255) / 256), blk, 0, stream>>>(agg, out, bn, gamma, beta,
                                                            total8, 1.0f / (float)N);
}